// Round 4
// baseline (322.727 us; speedup 1.0000x reference)
//
#include <hip/hip_runtime.h>

// Adder: base-10 digit addition with carry-lookahead.
// (B=524288, S=64) fp32 digits, index 0 = MSB, 63 = LSB.
// Mapping: one wave covers 4 rows per "unit" (unit = 256 floats = 1 KiB/array):
//   row r = lanes 16r..16r+15, lane j-of-row holds digits 4j..4j+3 (float4).
// Carry chain closed-form:
//   digit: g=(s>=10), p=(s==9) (mutually exclusive, s in 0..18 exact)
//   lane : 4-bit lookahead C4=(PG+G)^PG^G; bit4=group-gen; group-prop=(p4==0xF)
//   row  : one __ballot pair for all 4 rows; 16-bit lookahead per row,
//          bit-reversed to LSB-first; overflow past bit15 drops top carry
//          (matches reference).
// R3 post-mortem: short-lived waves (2 loads -> wait -> store -> exit) were
// latency-bound at ~2.3 TB/s. This version is persistent grid-stride with
// unroll so each wave keeps multiple 1 KiB loads in flight (copy-ubench style,
// 6.29 TB/s ceiling). Plain stores (nt store regressed R1->R3: write-back
// through L2/L3 overlaps better).

typedef float f32x4 __attribute__((ext_vector_type(4)));

constexpr int       BLOCKS        = 2048;
constexpr int       THREADS       = 256;
constexpr int       WAVES         = BLOCKS * (THREADS / 64);        // 8192
constexpr long long N_UNITS       = 524288LL * 64 / 256;            // 131072
constexpr int       UNITS_PER_WAVE = (int)(N_UNITS / WAVES);        // 16

__global__ __launch_bounds__(THREADS) void adder_kernel(
    const float* __restrict__ a,
    const float* __restrict__ b,
    float* __restrict__ out)
{
    const int lane = (int)(threadIdx.x & 63);
    const int wid  = (int)(blockIdx.x * 4 + (threadIdx.x >> 6));
    const int r    = lane >> 4;   // row within wave's 4-row unit
    const int j    = lane & 15;   // group index in row, j=0 most significant

#pragma unroll 4
    for (int i = 0; i < UNITS_PER_WAVE; ++i) {
        const long long unit = (long long)i * WAVES + wid;   // strided walk
        const long long base = unit * 256 + 4 * lane;        // 1 KiB/wave/array

        const f32x4 av = *(const f32x4*)(a + base);
        const f32x4 bv = *(const f32x4*)(b + base);

        const float s0 = av.x + bv.x;   // most significant of lane's group
        const float s1 = av.y + bv.y;
        const float s2 = av.z + bv.z;
        const float s3 = av.w + bv.w;   // least significant

        // 4-bit masks, LSB-first in group: bit0<->s3 ... bit3<->s0
        const unsigned g4 = (unsigned)(s3 >= 10.0f)
                          | ((unsigned)(s2 >= 10.0f) << 1)
                          | ((unsigned)(s1 >= 10.0f) << 2)
                          | ((unsigned)(s0 >= 10.0f) << 3);
        const unsigned p4 = (unsigned)(s3 == 9.0f)
                          | ((unsigned)(s2 == 9.0f) << 1)
                          | ((unsigned)(s1 == 9.0f) << 2)
                          | ((unsigned)(s0 == 9.0f) << 3);
        const unsigned pg4 = p4 | g4;
        const unsigned c4  = (pg4 + g4) ^ pg4 ^ g4;  // bit4 = group generate
        const bool Ggrp = (c4 >> 4) & 1u;
        const bool Pgrp = (p4 == 0xFu);

        // group G/P for all 4 rows of this wave in one ballot pair
        const unsigned long long Gl = __ballot(Ggrp);
        const unsigned long long Pl = __ballot(Pgrp);

        unsigned Gr = (unsigned)((Gl >> (16 * r)) & 0xFFFFull);
        unsigned Pr = (unsigned)((Pl >> (16 * r)) & 0xFFFFull);
        // lane j <-> LSB-first position k = 15-j : 16-bit reverse
        Gr = __brev(Gr) >> 16;
        Pr = __brev(Pr) >> 16;
        const unsigned PGr = Pr | Gr;
        const unsigned Cr  = (PGr + Gr) ^ PGr ^ Gr;  // carry-in per group

        const float cin = (float)((Cr >> (15 - j)) & 1u);

        // serial ripple through the lane's 4 digits, LSB (s3) first
        float u, c;
        f32x4 d;
        u = s3 + cin; c = (u >= 10.0f) ? 1.0f : 0.0f; d.w = u - 10.0f * c;
        u = s2 + c;   c = (u >= 10.0f) ? 1.0f : 0.0f; d.z = u - 10.0f * c;
        u = s1 + c;   c = (u >= 10.0f) ? 1.0f : 0.0f; d.y = u - 10.0f * c;
        u = s0 + c;   c = (u >= 10.0f) ? 1.0f : 0.0f; d.x = u - 10.0f * c;

        *(f32x4*)(out + base) = d;
    }
}

extern "C" void kernel_launch(void* const* d_in, const int* in_sizes, int n_in,
                              void* d_out, int out_size, void* d_ws, size_t ws_size,
                              hipStream_t stream) {
    const float* a = (const float*)d_in[0];
    const float* b = (const float*)d_in[1];
    float* out = (float*)d_out;
    adder_kernel<<<BLOCKS, THREADS, 0, stream>>>(a, b, out);
}